// Round 1
// 442.829 us; speedup vs baseline: 1.0239x; 1.0239x over previous
//
#include <hip/hip_runtime.h>
#include <cstdint>

// ---------------------------------------------------------------------------
// Types / helpers
// ---------------------------------------------------------------------------
typedef float floatx4 __attribute__((ext_vector_type(4)));
typedef __bf16 bf16x8 __attribute__((ext_vector_type(8)));

typedef const __attribute__((address_space(1))) void* gas_cvp;
typedef __attribute__((address_space(3))) void* las_vp;

__device__ __forceinline__ float bflo(unsigned int u) {
    return __builtin_bit_cast(float, u << 16);
}
__device__ __forceinline__ float bfhi(unsigned int u) {
    return __builtin_bit_cast(float, u & 0xffff0000u);
}
__device__ __forceinline__ unsigned short f2bf(float f) {
    unsigned int u = __builtin_bit_cast(unsigned int, f);
    u += 0x7fffu + ((u >> 16) & 1u);   // RNE (finite inputs)
    return (unsigned short)(u >> 16);
}
__device__ __forceinline__ bf16x8 ld8(const unsigned short* p) {
    return __builtin_bit_cast(bf16x8, *(const uint4*)p);
}
__device__ __forceinline__ floatx4 mfma32(bf16x8 a, bf16x8 b, floatx4 c) {
    return __builtin_amdgcn_mfma_f32_16x16x32_bf16(a, b, c, 0, 0, 0);
}
// async global->LDS, 16B per lane. LDS dest = wave-uniform base + lane*16.
__device__ __forceinline__ void load_lds16(const void* g, void* l) {
    __builtin_amdgcn_global_load_lds(
        (gas_cvp)(unsigned long long)g,
        (las_vp)(unsigned int)(unsigned long long)l,
        16, 0, 0);
}

// ---------------------------------------------------------------------------
// f32 -> bf16 converts
// ---------------------------------------------------------------------------
__global__ void cvt_f32_bf16(const float* __restrict__ in,
                             unsigned short* __restrict__ out, int n4) {
    int i = blockIdx.x * 256 + threadIdx.x;
    if (i < n4) {
        float4 v = ((const float4*)in)[i];
        ushort4 o;
        o.x = f2bf(v.x); o.y = f2bf(v.y); o.z = f2bf(v.z); o.w = f2bf(v.w);
        ((ushort4*)out)[i] = o;
    }
}

struct CvtJob { const float* src; unsigned short* dst; int n4; };
struct CvtJobs { CvtJob j[7]; };

__global__ void cvt_multi(CvtJobs jobs) {
    CvtJob jb = jobs.j[blockIdx.y];
    int i = blockIdx.x * 256 + threadIdx.x;
    if (i < jb.n4) {
        float4 v = ((const float4*)jb.src)[i];
        ushort4 o;
        o.x = f2bf(v.x); o.y = f2bf(v.y); o.z = f2bf(v.z); o.w = f2bf(v.w);
        ((ushort4*)jb.dst)[i] = o;
    }
}

// ---------------------------------------------------------------------------
// 256x256 8-phase BT GEMM:  C[m,n] = sum_k A[m,k] * B[n,k]   (N = 1280 fixed)
//
// 512 threads = 8 waves (2M x 4N), BK=64, LDS 128 KiB (A 64K + B 64K, each
// 2 buffers x 2 half-tiles x 16KB). Per K-tile: 4 phases (quadrants
// M0N0, M0N1, M1N1, M1N0), each phase = {ds_read frags | stage 1 half-tile
// (2x global_load_lds) | barrier | setprio(1) MFMA x16 setprio(0) | barrier}.
// Counted s_waitcnt vmcnt(4) once per K-tile (never 0 in-loop).
//
// Stage order (derived WAR-free): p0: A-h1(u+1)->other buf; p1: B-h1(u+1);
// p2: B-h0(u+2)->CURRENT buf (B reads of tile u retired at p1 barrier);
// p3: A-h0(u+2)->CURRENT buf (A reads retired at p2 barrier).
//
// LDS layout: per half-tile 16 subtiles of [16 rows x 32 cols] bf16 (1024B),
// subtile = (row16)*2 + colgrp. Swizzle: chunk-bytes bits[5:4] ^= row bits
// [2:1] -> ds_read_b128 frag loads are bank-conflict-free (8 lanes / 4-bank
// window = b128 optimum). global_load_lds writes linearly; the swizzle is
// applied by permuting the per-lane GLOBAL source chunk (both-sides rule).
// ---------------------------------------------------------------------------
struct GJob {
    const unsigned short* A;
    const unsigned short* B;
    void* C;
    int M, K;
    int rpb, bstride, roff;   // A row mapping (token packing)
    int bstart;               // first flat block id of this job
};
struct GArgs { GJob j[5]; };

#define GBAR() do { __builtin_amdgcn_s_barrier(); __builtin_amdgcn_sched_barrier(0); } while (0)

template <bool F32OUT>
__global__ __launch_bounds__(512, 2) void gemm256(GArgs args,
                                                  const float* __restrict__ bias) {
    const int tid = threadIdx.x;
    int jid = 0;
#pragma unroll
    for (int t = 1; t < 5; ++t)
        if ((int)blockIdx.x >= args.j[t].bstart) jid = t;
    const GJob jb = args.j[jid];
    const int K = jb.K;
    int b = (int)blockIdx.x - jb.bstart;
    {
        const int mt = (jb.M + 255) >> 8;
        const int nblk = mt * 5;
        if ((nblk & 7) == 0) b = (b & 7) * (nblk >> 3) + (b >> 3);  // XCD swizzle
    }
    const int by = b / 5, bx = b - by * 5;

    __shared__ unsigned short ldsA[32768];   // 64 KiB
    __shared__ unsigned short ldsB[32768];   // 64 KiB

    // ---- staging decode: thread t, load j covers LDS linear [j*8K + t*16, +16)
    // subtile s = j*8 + (t>>6); r = (t>>2)&15; stored chunk = (t&3)*16 bytes.
    // logical chunk = stored ^ ((r&6)<<3)  (involution; applied to global src)
    const int srow   = ((tid >> 7) << 4) + ((tid >> 2) & 15);          // 0..63
    const int schunk = ((tid & 3) << 4) ^ (((tid >> 2) & 6) << 3);     // bytes
    const int scol   = (((tid >> 6) & 1) << 5) + (schunk >> 1);        // elems

    const int Mloc = jb.M, rpbL = jb.rpb, bstrL = jb.bstride, roffL = jb.roff;
    auto maprow = [&](int r) -> size_t {
        r = (r < Mloc) ? r : (Mloc - 1);
        int blk = r / rpbL;
        return (size_t)(blk * bstrL + roffL + (r - blk * rpbL));
    };

    const unsigned short* pA[2][2];
    const unsigned short* pB[2][2];
    unsigned short* dA[2][2];
    unsigned short* dB[2][2];
#pragma unroll
    for (int h = 0; h < 2; ++h)
#pragma unroll
        for (int j = 0; j < 2; ++j) {
            const int r = h * 128 + j * 64 + srow;
            pA[h][j] = jb.A + maprow(by * 256 + r) * K + scol;
            pB[h][j] = jb.B + (size_t)(bx * 256 + r) * K + scol;
            dA[h][j] = &ldsA[h * 8192 + j * 4096 + tid * 8];
            dB[h][j] = &ldsB[h * 8192 + j * 4096 + tid * 8];
        }

    // ---- fragment-read decode
    const int lane = tid & 63, fr = lane & 15, g = lane >> 4;
    const int w = tid >> 6, wr = w & 1, wc = w >> 1;
    const int rb   = fr * 32 + ((g * 8) ^ ((fr & 6) << 2));            // shorts
    const int aoff = wr * 8192 + rb;
    const int boff = (wc >> 1) * 8192 + (wc & 1) * 4096 + rb;

    floatx4 acc[8][4] = {};
    bf16x8 af[4][2], bn0[2][2], bn1[2][2];

    const int KT = K >> 6;

    // ---- prologue: tile0 all 4 half-tiles, then tile1 {B-h0, A-h0}
    load_lds16(pA[0][0], dA[0][0]); load_lds16(pA[0][1], dA[0][1]);
    load_lds16(pA[1][0], dA[1][0]); load_lds16(pA[1][1], dA[1][1]);
    load_lds16(pB[0][0], dB[0][0]); load_lds16(pB[0][1], dB[0][1]);
    load_lds16(pB[1][0], dB[1][0]); load_lds16(pB[1][1], dB[1][1]);
    load_lds16(pB[0][0] + 64, dB[0][0] + 16384);
    load_lds16(pB[0][1] + 64, dB[0][1] + 16384);
    load_lds16(pA[0][0] + 64, dA[0][0] + 16384);
    load_lds16(pA[0][1] + 64, dA[0][1] + 16384);
    asm volatile("s_waitcnt vmcnt(4)" ::: "memory");
    GBAR();

    for (int u = 0; u < KT; ++u) {
        const int pb = (u & 1) << 14;     // read buffer base (shorts)
        const int qb = pb ^ 16384;        // other buffer
        const int k1 = (u + 1 < KT) ? (u + 1) : (KT - 1);
        const int k2 = (u + 2 < KT) ? (u + 2) : (KT - 1);

        // ---- phase 0: read A-M0 + B-N0 ; stage A-h1(u+1) -> qb
#pragma unroll
        for (int mi = 0; mi < 4; ++mi)
#pragma unroll
            for (int kk = 0; kk < 2; ++kk)
                af[mi][kk] = *(const bf16x8*)&ldsA[pb + aoff + (mi * 2 + kk) * 512];
#pragma unroll
        for (int nf = 0; nf < 2; ++nf)
#pragma unroll
            for (int kk = 0; kk < 2; ++kk)
                bn0[nf][kk] = *(const bf16x8*)&ldsB[pb + boff + (nf * 2 + kk) * 512];
        load_lds16(pA[1][0] + (size_t)k1 * 64, dA[1][0] + qb);
        load_lds16(pA[1][1] + (size_t)k1 * 64, dA[1][1] + qb);
        GBAR();
        __builtin_amdgcn_s_setprio(1);
#pragma unroll
        for (int kk = 0; kk < 2; ++kk)
#pragma unroll
            for (int mi = 0; mi < 4; ++mi)
#pragma unroll
                for (int nf = 0; nf < 2; ++nf)
                    acc[mi][nf] = mfma32(af[mi][kk], bn0[nf][kk], acc[mi][nf]);
        __builtin_amdgcn_s_setprio(0);
        GBAR();

        // ---- phase 1: read B-N1 ; stage B-h1(u+1) -> qb
#pragma unroll
        for (int nf = 0; nf < 2; ++nf)
#pragma unroll
            for (int kk = 0; kk < 2; ++kk)
                bn1[nf][kk] = *(const bf16x8*)&ldsB[pb + boff + ((nf + 2) * 2 + kk) * 512];
        load_lds16(pB[1][0] + (size_t)k1 * 64, dB[1][0] + qb);
        load_lds16(pB[1][1] + (size_t)k1 * 64, dB[1][1] + qb);
        GBAR();
        __builtin_amdgcn_s_setprio(1);
#pragma unroll
        for (int kk = 0; kk < 2; ++kk)
#pragma unroll
            for (int mi = 0; mi < 4; ++mi)
#pragma unroll
                for (int nf = 0; nf < 2; ++nf)
                    acc[mi][nf + 2] = mfma32(af[mi][kk], bn1[nf][kk], acc[mi][nf + 2]);
        __builtin_amdgcn_s_setprio(0);
        GBAR();

        // ---- phase 2: read A-M1 ; stage B-h0(u+2) -> pb (B reads retired @p1)
#pragma unroll
        for (int mi = 0; mi < 4; ++mi)
#pragma unroll
            for (int kk = 0; kk < 2; ++kk)
                af[mi][kk] = *(const bf16x8*)&ldsA[pb + aoff + ((mi + 4) * 2 + kk) * 512];
        load_lds16(pB[0][0] + (size_t)k2 * 64, dB[0][0] + pb);
        load_lds16(pB[0][1] + (size_t)k2 * 64, dB[0][1] + pb);
        GBAR();
        __builtin_amdgcn_s_setprio(1);
#pragma unroll
        for (int kk = 0; kk < 2; ++kk)
#pragma unroll
            for (int mi = 0; mi < 4; ++mi)
#pragma unroll
                for (int nf = 0; nf < 2; ++nf)
                    acc[mi + 4][nf + 2] = mfma32(af[mi][kk], bn1[nf][kk], acc[mi + 4][nf + 2]);
        __builtin_amdgcn_s_setprio(0);
        GBAR();

        // ---- phase 3: stage A-h0(u+2) -> pb (A reads retired @p2); MFMA M1N0
        load_lds16(pA[0][0] + (size_t)k2 * 64, dA[0][0] + pb);
        load_lds16(pA[0][1] + (size_t)k2 * 64, dA[0][1] + pb);
        GBAR();
        __builtin_amdgcn_s_setprio(1);
#pragma unroll
        for (int kk = 0; kk < 2; ++kk)
#pragma unroll
            for (int mi = 0; mi < 4; ++mi)
#pragma unroll
                for (int nf = 0; nf < 2; ++nf)
                    acc[mi + 4][nf] = mfma32(af[mi][kk], bn0[nf][kk], acc[mi + 4][nf]);
        __builtin_amdgcn_s_setprio(0);
        asm volatile("s_waitcnt vmcnt(4)" ::: "memory");   // tile u+1 fully landed
        GBAR();
    }
    asm volatile("s_waitcnt vmcnt(0)" ::: "memory");

    // ---- epilogue
    const int colBase = bx * 256 + wc * 64;
    const int rowBase = by * 256 + wr * 128;
    float bv[4] = {};
    if (F32OUT) {
#pragma unroll
        for (int nf = 0; nf < 4; ++nf) bv[nf] = bias[colBase + nf * 16 + fr];
    }
#pragma unroll
    for (int mi = 0; mi < 8; ++mi) {
#pragma unroll
        for (int nf = 0; nf < 4; ++nf) {
            const int col  = colBase + nf * 16 + fr;
            const int row0 = rowBase + mi * 16 + g * 4;
#pragma unroll
            for (int r = 0; r < 4; ++r) {
                const int row = row0 + r;
                if (row < Mloc) {
                    float v = acc[mi][nf][r];
                    if (F32OUT)
                        ((float*)jb.C)[(size_t)row * 1280 + col] = v + bv[nf];
                    else
                        ((unsigned short*)jb.C)[(size_t)row * 1280 + col] = f2bf(v);
                }
            }
        }
    }
}

// ---------------------------------------------------------------------------
// MFMA attention. Block = (q-tile of 32 rows) x (head) x (batch pair).
// ---------------------------------------------------------------------------
#define NT 77
#define NI 20
#define VSTR 104
#define ISTR 40

__global__ __launch_bounds__(256, 2) void attn_mfma(
    const unsigned short* __restrict__ q,    // [4*4096][1280]
    const unsigned short* __restrict__ kt,   // [4*77][1280]
    const unsigned short* __restrict__ vt,   // [4*77][1280]
    const unsigned short* __restrict__ kip,  // [4*20][1280]
    const unsigned short* __restrict__ vip,  // [4*20][1280]
    unsigned short* __restrict__ outp)       // [4*4096][1280]
{
    const int tid = threadIdx.x;
    const int qt = blockIdx.x;
    const int h  = blockIdx.y;
    const int pz = blockIdx.z;
    const int b0 = 2 * pz;
    const int lane  = tid & 63;
    const int w     = tid >> 6;
    const int bi    = w >> 1;
    const int strip = (w & 1) * 16;
    const int fr = lane & 15;
    const int g  = lane >> 4;

    __shared__ unsigned short sVt[2][64][VSTR];
    __shared__ unsigned short sVipt[2][64][ISTR];
    __shared__ unsigned short sP[2][32][VSTR];

    for (int i = tid; i < 2 * 64 * (VSTR - NT); i += 256) {
        int b = i / (64 * (VSTR - NT)); int rem = i % (64 * (VSTR - NT));
        sVt[b][rem / (VSTR - NT)][NT + rem % (VSTR - NT)] = 0;
    }
    for (int i = tid; i < 2 * 64 * (ISTR - NI); i += 256) {
        int b = i / (64 * (ISTR - NI)); int rem = i % (64 * (ISTR - NI));
        sVipt[b][rem / (ISTR - NI)][NI + rem % (ISTR - NI)] = 0;
    }
    for (int i = tid; i < 2 * 32 * (VSTR - 80); i += 256) {
        int b = i / (32 * (VSTR - 80)); int rem = i % (32 * (VSTR - 80));
        sP[b][rem / (VSTR - 80)][80 + rem % (VSTR - 80)] = 0;
    }

    for (int c = tid; c < 2 * 8 * NT; c += 256) {
        int b = c / (8 * NT); int rem = c % (8 * NT);
        int dc = rem / NT; int key = rem % NT;
        uint4 v = *(const uint4*)&vt[((size_t)((b0 + b) * NT + key)) * 1280 + h * 64 + dc * 8];
        unsigned int uu[4] = {v.x, v.y, v.z, v.w};
#pragma unroll
        for (int j = 0; j < 4; j++) {
            sVt[b][dc * 8 + 2 * j][key]     = (unsigned short)(uu[j] & 0xffffu);
            sVt[b][dc * 8 + 2 * j + 1][key] = (unsigned short)(uu[j] >> 16);
        }
    }
    for (int c = tid; c < 2 * 8 * NI; c += 256) {
        int b = c / (8 * NI); int rem = c % (8 * NI);
        int dc = rem / NI; int key = rem % NI;
        uint4 v = *(const uint4*)&vip[((size_t)((b0 + b) * NI + key)) * 1280 + h * 64 + dc * 8];
        unsigned int uu[4] = {v.x, v.y, v.z, v.w};
#pragma unroll
        for (int j = 0; j < 4; j++) {
            sVipt[b][dc * 8 + 2 * j][key]     = (unsigned short)(uu[j] & 0xffffu);
            sVipt[b][dc * 8 + 2 * j + 1][key] = (unsigned short)(uu[j] >> 16);
        }
    }

    const size_t qbase = ((size_t)((b0 + bi) * 4096 + qt * 32 + strip + fr)) * 1280 + h * 64;
    bf16x8 aq0 = ld8(&q[qbase + g * 8]);
    bf16x8 aq1 = ld8(&q[qbase + 32 + g * 8]);

    floatx4 sc[5] = {};
#pragma unroll
    for (int t = 0; t < 5; t++) {
        int key = t * 16 + fr; key = (key < NT) ? key : (NT - 1);
        const size_t kb = ((size_t)((b0 + bi) * NT + key)) * 1280 + h * 64;
        sc[t] = mfma32(aq0, ld8(&kt[kb + g * 8]), sc[t]);
        sc[t] = mfma32(aq1, ld8(&kt[kb + 32 + g * 8]), sc[t]);
    }

#pragma unroll
    for (int r = 0; r < 4; r++) {
        float m = -1e30f;
#pragma unroll
        for (int t = 0; t < 5; t++) {
            float v = sc[t][r] * 0.125f;
            if (t == 4 && fr >= 13) v = -1e30f;
            sc[t][r] = v;
            m = fmaxf(m, v);
        }
        m = fmaxf(m, __shfl_xor(m, 1));
        m = fmaxf(m, __shfl_xor(m, 2));
        m = fmaxf(m, __shfl_xor(m, 4));
        m = fmaxf(m, __shfl_xor(m, 8));
        float sum = 0.f;
#pragma unroll
        for (int t = 0; t < 5; t++) {
            float e = __expf(sc[t][r] - m);
            sc[t][r] = e;
            sum += e;
        }
        sum += __shfl_xor(sum, 1);
        sum += __shfl_xor(sum, 2);
        sum += __shfl_xor(sum, 4);
        sum += __shfl_xor(sum, 8);
        float inv = 1.f / sum;
#pragma unroll
        for (int t = 0; t < 5; t++)
            sP[bi][strip + g * 4 + r][t * 16 + fr] = f2bf(sc[t][r] * inv);
    }
    __syncthreads();

    {
        unsigned int* p0 = (unsigned int*)&sP[0][0][0];
        unsigned int* p1 = (unsigned int*)&sP[1][0][0];
        for (int i = tid; i < 32 * VSTR / 2; i += 256) {
            unsigned int a = p0[i], b = p1[i];
            unsigned short r0 = f2bf(0.5f * (bflo(a) + bflo(b)));
            unsigned short r1 = f2bf(0.5f * (bfhi(a) + bfhi(b)));
            p1[i] = (unsigned int)r0 | ((unsigned int)r1 << 16);
        }
    }
    __syncthreads();

    floatx4 accO[4] = {};
    {
        const unsigned short* prow = &sP[bi][strip + fr][0];
        bf16x8 pa0 = ld8(prow + g * 8);
        bf16x8 pa1 = ld8(prow + 32 + g * 8);
        bf16x8 pa2 = ld8(prow + 64 + g * 8);
#pragma unroll
        for (int dt = 0; dt < 4; dt++) {
            const unsigned short* vrow = &sVt[bi][dt * 16 + fr][0];
            accO[dt] = mfma32(pa0, ld8(vrow + g * 8), accO[dt]);
            accO[dt] = mfma32(pa1, ld8(vrow + 32 + g * 8), accO[dt]);
            accO[dt] = mfma32(pa2, ld8(vrow + 64 + g * 8), accO[dt]);
        }
    }

    floatx4 si[2] = {};
#pragma unroll
    for (int t = 0; t < 2; t++) {
        int key = t * 16 + fr; key = (key < NI) ? key : (NI - 1);
        const size_t kb = ((size_t)((b0 + bi) * NI + key)) * 1280 + h * 64;
        si[t] = mfma32(aq0, ld8(&kip[kb + g * 8]), si[t]);
        si[t] = mfma32(aq1, ld8(&kip[kb + 32 + g * 8]), si[t]);
    }
#pragma unroll
    for (int r = 0; r < 4; r++) {
        float v0 = si[0][r] * 0.125f;
        float v1 = (fr >= 4) ? -1e30f : si[1][r] * 0.125f;
        float m = fmaxf(v0, v1);
        m = fmaxf(m, __shfl_xor(m, 1));
        m = fmaxf(m, __shfl_xor(m, 2));
        m = fmaxf(m, __shfl_xor(m, 4));
        m = fmaxf(m, __shfl_xor(m, 8));
        float e0 = __expf(v0 - m), e1 = __expf(v1 - m);
        float s = e0 + e1;
        s += __shfl_xor(s, 1);
        s += __shfl_xor(s, 2);
        s += __shfl_xor(s, 4);
        s += __shfl_xor(s, 8);
        float inv = 1.f / s;
        si[0][r] = e0 * inv;
        si[1][r] = e1 * inv;
    }
    __syncthreads();

#pragma unroll
    for (int r = 0; r < 4; r++) {
        sP[bi][strip + g * 4 + r][fr]      = f2bf(si[0][r]);
        sP[bi][strip + g * 4 + r][16 + fr] = f2bf(si[1][r]);
    }
    __syncthreads();

    for (int i = tid; i < 32 * 16; i += 256) {
        int r = i >> 4, kk = i & 15;
        unsigned int* p0 = (unsigned int*)&sP[0][r][0];
        unsigned int* p1 = (unsigned int*)&sP[1][r][0];
        unsigned int a = p0[kk], b = p1[kk];
        unsigned short r0 = f2bf(0.5f * (bflo(a) + bflo(b)));
        unsigned short r1 = f2bf(0.5f * (bfhi(a) + bfhi(b)));
        p1[kk] = (unsigned int)r0 | ((unsigned int)r1 << 16);
    }
    __syncthreads();

    if (bi == 1) {
        const unsigned short* prow = &sP[1][strip + fr][0];
        bf16x8 pip = ld8(prow + g * 8);
#pragma unroll
        for (int dt = 0; dt < 4; dt++)
            accO[dt] = mfma32(pip, ld8(&sVipt[1][dt * 16 + fr][g * 8]), accO[dt]);
    }

    const size_t orow0 = (size_t)((b0 + bi) * 4096 + qt * 32 + strip);
#pragma unroll
    for (int dt = 0; dt < 4; dt++) {
        int col = h * 64 + dt * 16 + fr;
#pragma unroll
        for (int r = 0; r < 4; r++)
            outp[(orow0 + g * 4 + r) * 1280 + col] = f2bf(accO[dt][r]);
    }
}

// ---------------------------------------------------------------------------
// Host launch
// ---------------------------------------------------------------------------
extern "C" void kernel_launch(void* const* d_in, const int* in_sizes, int n_in,
                              void* d_out, int out_size, void* d_ws, size_t ws_size,
                              hipStream_t stream) {
    const float* hs   = (const float*)d_in[0];
    const float* ehs  = (const float*)d_in[1];
    const float* Wq   = (const float*)d_in[2];
    const float* Wk   = (const float*)d_in[3];
    const float* Wv   = (const float*)d_in[4];
    const float* Wkip = (const float*)d_in[5];
    const float* Wvip = (const float*)d_in[6];
    const float* Wo   = (const float*)d_in[7];
    const float* bo   = (const float*)d_in[8];

    char* w = (char*)d_ws;
    size_t off = 0;
    auto alloc = [&](size_t bytes) {
        char* pp = w + off;
        off += (bytes + 255) & ~(size_t)255;
        return pp;
    };
    unsigned short* hs_bf   = (unsigned short*)alloc(16384ull * 1280 * 2);
    unsigned short* q_bf    = (unsigned short*)alloc(16384ull * 1280 * 2);
    unsigned short* at_bf   = (unsigned short*)alloc(16384ull * 1280 * 2);
    unsigned short* ehs_bf  = (unsigned short*)alloc(4ull * 97 * 2048 * 2);
    unsigned short* Wq_bf   = (unsigned short*)alloc(1280ull * 1280 * 2);
    unsigned short* Wk_bf   = (unsigned short*)alloc(1280ull * 2048 * 2);
    unsigned short* Wv_bf   = (unsigned short*)alloc(1280ull * 2048 * 2);
    unsigned short* Wkip_bf = (unsigned short*)alloc(1280ull * 2048 * 2);
    unsigned short* Wvip_bf = (unsigned short*)alloc(1280ull * 2048 * 2);
    unsigned short* Wo_bf   = (unsigned short*)alloc(1280ull * 1280 * 2);
    unsigned short* kt  = (unsigned short*)alloc(308ull * 1280 * 2);
    unsigned short* vt  = (unsigned short*)alloc(308ull * 1280 * 2);
    unsigned short* kip = (unsigned short*)alloc(80ull * 1280 * 2);
    unsigned short* vip = (unsigned short*)alloc(80ull * 1280 * 2);

    // hs convert (big, own launch)
    cvt_f32_bf16<<<dim3(20480, 1, 1), 256, 0, stream>>>(hs, hs_bf, 16384 * 1280 / 4);

    // all small converts in one launch (7 jobs)
    CvtJobs cj{};
    cj.j[0] = CvtJob{ehs,  ehs_bf,  (int)(4ull * 97 * 2048 / 4)};
    cj.j[1] = CvtJob{Wq,   Wq_bf,   1280 * 1280 / 4};
    cj.j[2] = CvtJob{Wk,   Wk_bf,   1280 * 2048 / 4};
    cj.j[3] = CvtJob{Wv,   Wv_bf,   1280 * 2048 / 4};
    cj.j[4] = CvtJob{Wkip, Wkip_bf, 1280 * 2048 / 4};
    cj.j[5] = CvtJob{Wvip, Wvip_bf, 1280 * 2048 / 4};
    cj.j[6] = CvtJob{Wo,   Wo_bf,   1280 * 1280 / 4};
    cvt_multi<<<dim3(2560, 7, 1), 256, 0, stream>>>(cj);

    // q-proj + 4 k/v projections in ONE flat dispatch.
    // Small jobs first (blocks 0..29) so their longer K=2048 overlaps the tail.
    // Block counts: k 2x5=10, v 10, kip 1x5=5, vip 5, q 64x5=320 -> 350 total.
    GArgs g1{};
    g1.j[0] = GJob{ehs_bf, Wk_bf,   (void*)kt,    308, 2048,    77, 97,  0,  0};
    g1.j[1] = GJob{ehs_bf, Wv_bf,   (void*)vt,    308, 2048,    77, 97,  0, 10};
    g1.j[2] = GJob{ehs_bf, Wkip_bf, (void*)kip,    80, 2048,    20, 97, 77, 20};
    g1.j[3] = GJob{ehs_bf, Wvip_bf, (void*)vip,    80, 2048,    20, 97, 77, 25};
    g1.j[4] = GJob{hs_bf,  Wq_bf,   (void*)q_bf, 16384, 1280, 16384,  0,  0, 30};
    gemm256<false><<<dim3(350, 1, 1), 512, 0, stream>>>(g1, nullptr);

    // fused MFMA attention (text + ip, blend, odd-batch ip add)
    attn_mfma<<<dim3(128, 20, 2), 256, 0, stream>>>(q_bf, kt, vt, kip, vip, at_bf);

    // out = attn @ Wo^T + bo  (f32 output), 64x5 = 320 blocks
    GArgs g2{};
    g2.j[0] = GJob{at_bf, Wo_bf, d_out, 16384, 1280, 16384, 0, 0, 0};
    for (int t = 1; t < 5; ++t) g2.j[t].bstart = 0x7fffffff;
    gemm256<true><<<dim3(320, 1, 1), 512, 0, stream>>>(g2, bo);
}

// Round 2
// 440.093 us; speedup vs baseline: 1.0303x; 1.0062x over previous
//
#include <hip/hip_runtime.h>
#include <cstdint>

// ---------------------------------------------------------------------------
// Types / helpers
// ---------------------------------------------------------------------------
typedef float floatx4 __attribute__((ext_vector_type(4)));
typedef __bf16 bf16x8 __attribute__((ext_vector_type(8)));

typedef const __attribute__((address_space(1))) void* gas_cvp;
typedef __attribute__((address_space(3))) void* las_vp;

__device__ __forceinline__ float bflo(unsigned int u) {
    return __builtin_bit_cast(float, u << 16);
}
__device__ __forceinline__ float bfhi(unsigned int u) {
    return __builtin_bit_cast(float, u & 0xffff0000u);
}
__device__ __forceinline__ unsigned short f2bf(float f) {
    unsigned int u = __builtin_bit_cast(unsigned int, f);
    u += 0x7fffu + ((u >> 16) & 1u);   // RNE (finite inputs)
    return (unsigned short)(u >> 16);
}
__device__ __forceinline__ bf16x8 ld8(const unsigned short* p) {
    return __builtin_bit_cast(bf16x8, *(const uint4*)p);
}
__device__ __forceinline__ floatx4 mfma32(bf16x8 a, bf16x8 b, floatx4 c) {
    return __builtin_amdgcn_mfma_f32_16x16x32_bf16(a, b, c, 0, 0, 0);
}
// async global->LDS, 16B per lane. LDS dest = wave-uniform base + lane*16.
__device__ __forceinline__ void load_lds16(const void* g, void* l) {
    __builtin_amdgcn_global_load_lds(
        (gas_cvp)(unsigned long long)g,
        (las_vp)(unsigned int)(unsigned long long)l,
        16, 0, 0);
}

// ---------------------------------------------------------------------------
// f32 -> bf16 converts
// ---------------------------------------------------------------------------
__global__ void cvt_f32_bf16(const float* __restrict__ in,
                             unsigned short* __restrict__ out, int n4) {
    int i = blockIdx.x * 256 + threadIdx.x;
    if (i < n4) {
        float4 v = ((const float4*)in)[i];
        ushort4 o;
        o.x = f2bf(v.x); o.y = f2bf(v.y); o.z = f2bf(v.z); o.w = f2bf(v.w);
        ((ushort4*)out)[i] = o;
    }
}

struct CvtJob { const float* src; unsigned short* dst; int n4; };
struct CvtJobs { CvtJob j[6]; };

__global__ void cvt_multi(CvtJobs jobs) {
    CvtJob jb = jobs.j[blockIdx.y];
    int i = blockIdx.x * 256 + threadIdx.x;
    if (i < jb.n4) {
        float4 v = ((const float4*)jb.src)[i];
        ushort4 o;
        o.x = f2bf(v.x); o.y = f2bf(v.y); o.z = f2bf(v.z); o.w = f2bf(v.w);
        ((ushort4*)jb.dst)[i] = o;
    }
}

// ehs [4][97][2048] f32 -> text_pad [4*96][2048] bf16 (rows 77..95/batch = 0)
//                       -> ip_pad   [4*32][2048] bf16 (rows 20..31/batch = 0)
__global__ void cvt_ehs(const float* __restrict__ ehs,
                        unsigned short* __restrict__ text,
                        unsigned short* __restrict__ ip) {
    int i = blockIdx.x * 256 + threadIdx.x;   // ushort4 units
    if (i < 384 * 512) {
        int r = i >> 9, c = i & 511;
        int b = r / 96, t = r - b * 96;
        ushort4 o = {0, 0, 0, 0};
        if (t < 77) {
            float4 v = *(const float4*)&ehs[((size_t)(b * 97 + t)) * 2048 + c * 4];
            o.x = f2bf(v.x); o.y = f2bf(v.y); o.z = f2bf(v.z); o.w = f2bf(v.w);
        }
        ((ushort4*)text)[i] = o;
    } else {
        int i2 = i - 384 * 512;
        if (i2 < 128 * 512) {
            int r = i2 >> 9, c = i2 & 511;
            int b = r >> 5, t = r & 31;
            ushort4 o = {0, 0, 0, 0};
            if (t < 20) {
                float4 v = *(const float4*)&ehs[((size_t)(b * 97 + 77 + t)) * 2048 + c * 4];
                o.x = f2bf(v.x); o.y = f2bf(v.y); o.z = f2bf(v.z); o.w = f2bf(v.w);
            }
            ((ushort4*)ip)[i2] = o;
        }
    }
}

// ---------------------------------------------------------------------------
// 256x256 8-phase BT GEMM:  C[m,n] = sum_k A[m,k] * B[n,k]
// Generic per-job: N = nt*256, C leading dim ldc, B rows clamped to Bn.
// 512 threads = 8 waves (2M x 4N), BK=64, LDS 128 KiB double-buffered.
// Per K-tile: 4 phases (quadrants), counted vmcnt(4) once per K-tile.
// LDS 16x32-subtiled with chunk^row XOR swizzle (bank-conflict-free b128),
// applied on the pre-swizzled GLOBAL source (gload_lds writes linearly).
// ---------------------------------------------------------------------------
struct GJob {
    const unsigned short* A;
    const unsigned short* B;
    void* C;
    int M, K;
    int Bn;      // B row count (clamp)
    int nt;      // N tiles of 256
    int ldc;     // C leading dimension
    int bstart;  // first flat block id
};
struct GArgs { GJob j[5]; };

#define GBAR() do { __builtin_amdgcn_s_barrier(); __builtin_amdgcn_sched_barrier(0); } while (0)

template <bool F32OUT>
__global__ __launch_bounds__(512, 2) void gemm256(GArgs args,
                                                  const float* __restrict__ bias) {
    const int tid = threadIdx.x;
    int jid = 0;
#pragma unroll
    for (int t = 1; t < 5; ++t)
        if ((int)blockIdx.x >= args.j[t].bstart) jid = t;
    const GJob jb = args.j[jid];
    const int K = jb.K;
    int b = (int)blockIdx.x - jb.bstart;
    {
        const int mt = (jb.M + 255) >> 8;
        const int nblk = mt * jb.nt;
        if ((nblk & 7) == 0) b = (b & 7) * (nblk >> 3) + (b >> 3);  // XCD swizzle
    }
    const int by = b / jb.nt, bx = b - by * jb.nt;

    __shared__ unsigned short ldsA[32768];   // 64 KiB
    __shared__ unsigned short ldsB[32768];   // 64 KiB

    // staging decode: thread t stages 16B; stored chunk = (t&3), logical chunk
    // = stored ^ ((r&6)>>1)  (involution applied on global source address)
    const int srow   = ((tid >> 7) << 4) + ((tid >> 2) & 15);          // 0..63
    const int schunk = ((tid & 3) << 4) ^ (((tid >> 2) & 6) << 3);     // bytes
    const int scol   = (((tid >> 6) & 1) << 5) + (schunk >> 1);        // elems

    const int Mloc = jb.M, BnL = jb.Bn;

    const unsigned short* pA[2][2];
    const unsigned short* pB[2][2];
    unsigned short* dA[2][2];
    unsigned short* dB[2][2];
#pragma unroll
    for (int h = 0; h < 2; ++h)
#pragma unroll
        for (int j = 0; j < 2; ++j) {
            const int r = h * 128 + j * 64 + srow;
            int ra = by * 256 + r;  ra = (ra < Mloc) ? ra : (Mloc - 1);
            int rb2 = bx * 256 + r; rb2 = (rb2 < BnL) ? rb2 : (BnL - 1);
            pA[h][j] = jb.A + (size_t)ra * K + scol;
            pB[h][j] = jb.B + (size_t)rb2 * K + scol;
            dA[h][j] = &ldsA[h * 8192 + j * 4096 + tid * 8];
            dB[h][j] = &ldsB[h * 8192 + j * 4096 + tid * 8];
        }

    // fragment-read decode
    const int lane = tid & 63, fr = lane & 15, g = lane >> 4;
    const int w = tid >> 6, wr = w & 1, wc = w >> 1;
    const int rb   = fr * 32 + ((g * 8) ^ ((fr & 6) << 2));            // shorts
    const int aoff = wr * 8192 + rb;
    const int boff = (wc >> 1) * 8192 + (wc & 1) * 4096 + rb;

    floatx4 acc[8][4] = {};
    bf16x8 af[4][2], bn0[2][2], bn1[2][2];

    const int KT = K >> 6;

    // prologue: tile0 all 4 half-tiles, then tile1 {B-h0, A-h0}
    load_lds16(pA[0][0], dA[0][0]); load_lds16(pA[0][1], dA[0][1]);
    load_lds16(pA[1][0], dA[1][0]); load_lds16(pA[1][1], dA[1][1]);
    load_lds16(pB[0][0], dB[0][0]); load_lds16(pB[0][1], dB[0][1]);
    load_lds16(pB[1][0], dB[1][0]); load_lds16(pB[1][1], dB[1][1]);
    load_lds16(pB[0][0] + 64, dB[0][0] + 16384);
    load_lds16(pB[0][1] + 64, dB[0][1] + 16384);
    load_lds16(pA[0][0] + 64, dA[0][0] + 16384);
    load_lds16(pA[0][1] + 64, dA[0][1] + 16384);
    asm volatile("s_waitcnt vmcnt(4)" ::: "memory");
    GBAR();

    for (int u = 0; u < KT; ++u) {
        const int pb = (u & 1) << 14;     // read buffer base (shorts)
        const int qb = pb ^ 16384;        // other buffer
        const int k1 = (u + 1 < KT) ? (u + 1) : (KT - 1);
        const int k2 = (u + 2 < KT) ? (u + 2) : (KT - 1);

        // phase 0: read A-M0 + B-N0 ; stage A-h1(u+1) -> qb
#pragma unroll
        for (int mi = 0; mi < 4; ++mi)
#pragma unroll
            for (int kk = 0; kk < 2; ++kk)
                af[mi][kk] = *(const bf16x8*)&ldsA[pb + aoff + (mi * 2 + kk) * 512];
#pragma unroll
        for (int nf = 0; nf < 2; ++nf)
#pragma unroll
            for (int kk = 0; kk < 2; ++kk)
                bn0[nf][kk] = *(const bf16x8*)&ldsB[pb + boff + (nf * 2 + kk) * 512];
        load_lds16(pA[1][0] + (size_t)k1 * 64, dA[1][0] + qb);
        load_lds16(pA[1][1] + (size_t)k1 * 64, dA[1][1] + qb);
        GBAR();
        __builtin_amdgcn_s_setprio(1);
#pragma unroll
        for (int kk = 0; kk < 2; ++kk)
#pragma unroll
            for (int mi = 0; mi < 4; ++mi)
#pragma unroll
                for (int nf = 0; nf < 2; ++nf)
                    acc[mi][nf] = mfma32(af[mi][kk], bn0[nf][kk], acc[mi][nf]);
        __builtin_amdgcn_s_setprio(0);
        GBAR();

        // phase 1: read B-N1 ; stage B-h1(u+1) -> qb
#pragma unroll
        for (int nf = 0; nf < 2; ++nf)
#pragma unroll
            for (int kk = 0; kk < 2; ++kk)
                bn1[nf][kk] = *(const bf16x8*)&ldsB[pb + boff + ((nf + 2) * 2 + kk) * 512];
        load_lds16(pB[1][0] + (size_t)k1 * 64, dB[1][0] + qb);
        load_lds16(pB[1][1] + (size_t)k1 * 64, dB[1][1] + qb);
        GBAR();
        __builtin_amdgcn_s_setprio(1);
#pragma unroll
        for (int kk = 0; kk < 2; ++kk)
#pragma unroll
            for (int mi = 0; mi < 4; ++mi)
#pragma unroll
                for (int nf = 0; nf < 2; ++nf)
                    acc[mi][nf + 2] = mfma32(af[mi][kk], bn1[nf][kk], acc[mi][nf + 2]);
        __builtin_amdgcn_s_setprio(0);
        GBAR();

        // phase 2: read A-M1 ; stage B-h0(u+2) -> pb (B reads retired @p1)
#pragma unroll
        for (int mi = 0; mi < 4; ++mi)
#pragma unroll
            for (int kk = 0; kk < 2; ++kk)
                af[mi][kk] = *(const bf16x8*)&ldsA[pb + aoff + ((mi + 4) * 2 + kk) * 512];
        load_lds16(pB[0][0] + (size_t)k2 * 64, dB[0][0] + pb);
        load_lds16(pB[0][1] + (size_t)k2 * 64, dB[0][1] + pb);
        GBAR();
        __builtin_amdgcn_s_setprio(1);
#pragma unroll
        for (int kk = 0; kk < 2; ++kk)
#pragma unroll
            for (int mi = 0; mi < 4; ++mi)
#pragma unroll
                for (int nf = 0; nf < 2; ++nf)
                    acc[mi + 4][nf + 2] = mfma32(af[mi][kk], bn1[nf][kk], acc[mi + 4][nf + 2]);
        __builtin_amdgcn_s_setprio(0);
        GBAR();

        // phase 3: stage A-h0(u+2) -> pb (A reads retired @p2); MFMA M1N0
        load_lds16(pA[0][0] + (size_t)k2 * 64, dA[0][0] + pb);
        load_lds16(pA[0][1] + (size_t)k2 * 64, dA[0][1] + pb);
        GBAR();
        __builtin_amdgcn_s_setprio(1);
#pragma unroll
        for (int kk = 0; kk < 2; ++kk)
#pragma unroll
            for (int mi = 0; mi < 4; ++mi)
#pragma unroll
                for (int nf = 0; nf < 2; ++nf)
                    acc[mi + 4][nf] = mfma32(af[mi][kk], bn0[nf][kk], acc[mi + 4][nf]);
        __builtin_amdgcn_s_setprio(0);
        asm volatile("s_waitcnt vmcnt(4)" ::: "memory");   // tile u+1 fully landed
        GBAR();
    }
    asm volatile("s_waitcnt vmcnt(0)" ::: "memory");

    // epilogue
    const int colBase = bx * 256 + wc * 64;
    const int rowBase = by * 256 + wr * 128;
    const int ldc = jb.ldc;
    float bv[4] = {};
    if (F32OUT) {
#pragma unroll
        for (int nf = 0; nf < 4; ++nf) bv[nf] = bias[colBase + nf * 16 + fr];
    }
#pragma unroll
    for (int mi = 0; mi < 8; ++mi) {
#pragma unroll
        for (int nf = 0; nf < 4; ++nf) {
            const int col  = colBase + nf * 16 + fr;
            const int row0 = rowBase + mi * 16 + g * 4;
#pragma unroll
            for (int r = 0; r < 4; ++r) {
                const int row = row0 + r;
                if (row < Mloc) {
                    float v = acc[mi][nf][r];
                    if (F32OUT)
                        ((float*)jb.C)[(size_t)row * ldc + col] = v + bv[nf];
                    else
                        ((unsigned short*)jb.C)[(size_t)row * ldc + col] = f2bf(v);
                }
            }
        }
    }
}

// ---------------------------------------------------------------------------
// MFMA attention. Block = (q-tile of 32 rows) x (head) x (batch pair).
// K is read from kt [4*96][1280] (zero-padded keys), V^T directly from global
// vtT [1280][512] (col = b*96+key, zero-padded) -- no LDS V staging.
// ---------------------------------------------------------------------------
#define NT 77
#define NI 20

__global__ __launch_bounds__(256, 4) void attn_mfma(
    const unsigned short* __restrict__ q,    // [4*4096][1280]
    const unsigned short* __restrict__ kt,   // [4*96][1280]
    const unsigned short* __restrict__ vtT,  // [1280][512]
    const unsigned short* __restrict__ kip,  // [4*32][1280]
    const unsigned short* __restrict__ ipT,  // [1280][256]
    unsigned short* __restrict__ outp)       // [4*4096][1280]
{
    const int tid = threadIdx.x;
    const int qt = blockIdx.x;
    const int h  = blockIdx.y;
    const int pz = blockIdx.z;
    const int b0 = 2 * pz;
    const int lane  = tid & 63;
    const int w     = tid >> 6;
    const int bi    = w >> 1;
    const int strip = (w & 1) * 16;
    const int fr = lane & 15;
    const int g  = lane >> 4;

    __shared__ unsigned short sP[2][32][104];

    // zero P pad cols 80..103 (PV third chunk covers keys 64..95)
    for (int i = tid; i < 2 * 32 * 24; i += 256) {
        int b = i / (32 * 24); int rem = i % (32 * 24);
        sP[b][rem / 24][80 + rem % 24] = 0;
    }

    const size_t qbase = ((size_t)((b0 + bi) * 4096 + qt * 32 + strip + fr)) * 1280 + h * 64;
    bf16x8 aq0 = ld8(&q[qbase + g * 8]);
    bf16x8 aq1 = ld8(&q[qbase + 32 + g * 8]);

    floatx4 sc[5] = {};
#pragma unroll
    for (int t = 0; t < 5; t++) {
        int key = t * 16 + fr;                      // <= 79 < 96 (padded)
        const size_t kb = ((size_t)((b0 + bi) * 96 + key)) * 1280 + h * 64;
        sc[t] = mfma32(aq0, ld8(&kt[kb + g * 8]), sc[t]);
        sc[t] = mfma32(aq1, ld8(&kt[kb + 32 + g * 8]), sc[t]);
    }

#pragma unroll
    for (int r = 0; r < 4; r++) {
        float m = -1e30f;
#pragma unroll
        for (int t = 0; t < 5; t++) {
            float v = sc[t][r] * 0.125f;
            if (t == 4 && fr >= 13) v = -1e30f;     // keys 77..79 masked
            sc[t][r] = v;
            m = fmaxf(m, v);
        }
        m = fmaxf(m, __shfl_xor(m, 1));
        m = fmaxf(m, __shfl_xor(m, 2));
        m = fmaxf(m, __shfl_xor(m, 4));
        m = fmaxf(m, __shfl_xor(m, 8));
        float sum = 0.f;
#pragma unroll
        for (int t = 0; t < 5; t++) {
            float e = __expf(sc[t][r] - m);
            sc[t][r] = e;
            sum += e;
        }
        sum += __shfl_xor(sum, 1);
        sum += __shfl_xor(sum, 2);
        sum += __shfl_xor(sum, 4);
        sum += __shfl_xor(sum, 8);
        float inv = 1.f / sum;
#pragma unroll
        for (int t = 0; t < 5; t++)
            sP[bi][strip + g * 4 + r][t * 16 + fr] = f2bf(sc[t][r] * inv);
    }
    __syncthreads();

    // blend: p[b0+1] = 0.5*(p[b0] + p[b0+1])
    {
        unsigned int* p0 = (unsigned int*)&sP[0][0][0];
        unsigned int* p1 = (unsigned int*)&sP[1][0][0];
        for (int i = tid; i < 32 * 104 / 2; i += 256) {
            unsigned int a = p0[i], b = p1[i];
            unsigned short r0 = f2bf(0.5f * (bflo(a) + bflo(b)));
            unsigned short r1 = f2bf(0.5f * (bfhi(a) + bfhi(b)));
            p1[i] = (unsigned int)r0 | ((unsigned int)r1 << 16);
        }
    }
    __syncthreads();

    floatx4 accO[4] = {};
    {
        const unsigned short* prow = &sP[bi][strip + fr][0];
        bf16x8 pa0 = ld8(prow + g * 8);
        bf16x8 pa1 = ld8(prow + 32 + g * 8);
        bf16x8 pa2 = ld8(prow + 64 + g * 8);
        const int vcol = (b0 + bi) * 96;
#pragma unroll
        for (int dt = 0; dt < 4; dt++) {
            const unsigned short* vrow = &vtT[(size_t)(h * 64 + dt * 16 + fr) * 512 + vcol];
            accO[dt] = mfma32(pa0, ld8(vrow + g * 8), accO[dt]);
            accO[dt] = mfma32(pa1, ld8(vrow + 32 + g * 8), accO[dt]);
            accO[dt] = mfma32(pa2, ld8(vrow + 64 + g * 8), accO[dt]);
        }
    }

    floatx4 si[2] = {};
#pragma unroll
    for (int t = 0; t < 2; t++) {
        int key = t * 16 + fr;                      // < 32 (padded)
        const size_t kb = ((size_t)((b0 + bi) * 32 + key)) * 1280 + h * 64;
        si[t] = mfma32(aq0, ld8(&kip[kb + g * 8]), si[t]);
        si[t] = mfma32(aq1, ld8(&kip[kb + 32 + g * 8]), si[t]);
    }
#pragma unroll
    for (int r = 0; r < 4; r++) {
        float v0 = si[0][r] * 0.125f;
        float v1 = (fr >= 4) ? -1e30f : si[1][r] * 0.125f;
        float m = fmaxf(v0, v1);
        m = fmaxf(m, __shfl_xor(m, 1));
        m = fmaxf(m, __shfl_xor(m, 2));
        m = fmaxf(m, __shfl_xor(m, 4));
        m = fmaxf(m, __shfl_xor(m, 8));
        float e0 = __expf(v0 - m), e1 = __expf(v1 - m);
        float s = e0 + e1;
        s += __shfl_xor(s, 1);
        s += __shfl_xor(s, 2);
        s += __shfl_xor(s, 4);
        s += __shfl_xor(s, 8);
        float inv = 1.f / s;
        si[0][r] = e0 * inv;
        si[1][r] = e1 * inv;
    }
    __syncthreads();

#pragma unroll
    for (int r = 0; r < 4; r++) {
        sP[bi][strip + g * 4 + r][fr]      = f2bf(si[0][r]);
        sP[bi][strip + g * 4 + r][16 + fr] = f2bf(si[1][r]);
    }
    __syncthreads();

    for (int i = tid; i < 32 * 16; i += 256) {
        int r = i >> 4, kk = i & 15;
        unsigned int* p0 = (unsigned int*)&sP[0][r][0];
        unsigned int* p1 = (unsigned int*)&sP[1][r][0];
        unsigned int a = p0[kk], b = p1[kk];
        unsigned short r0 = f2bf(0.5f * (bflo(a) + bflo(b)));
        unsigned short r1 = f2bf(0.5f * (bfhi(a) + bfhi(b)));
        p1[kk] = (unsigned int)r0 | ((unsigned int)r1 << 16);
    }
    __syncthreads();

    if (bi == 1) {
        const unsigned short* prow = &sP[1][strip + fr][0];
        bf16x8 pip = ld8(prow + g * 8);
        const int icol = (b0 + 1) * 32;
#pragma unroll
        for (int dt = 0; dt < 4; dt++)
            accO[dt] = mfma32(pip,
                              ld8(&ipT[(size_t)(h * 64 + dt * 16 + fr) * 256 + icol + g * 8]),
                              accO[dt]);
    }

    const size_t orow0 = (size_t)((b0 + bi) * 4096 + qt * 32 + strip);
#pragma unroll
    for (int dt = 0; dt < 4; dt++) {
        int col = h * 64 + dt * 16 + fr;
#pragma unroll
        for (int r = 0; r < 4; r++)
            outp[(orow0 + g * 4 + r) * 1280 + col] = f2bf(accO[dt][r]);
    }
}

// ---------------------------------------------------------------------------
// Host launch
// ---------------------------------------------------------------------------
extern "C" void kernel_launch(void* const* d_in, const int* in_sizes, int n_in,
                              void* d_out, int out_size, void* d_ws, size_t ws_size,
                              hipStream_t stream) {
    const float* hs   = (const float*)d_in[0];
    const float* ehs  = (const float*)d_in[1];
    const float* Wq   = (const float*)d_in[2];
    const float* Wk   = (const float*)d_in[3];
    const float* Wv   = (const float*)d_in[4];
    const float* Wkip = (const float*)d_in[5];
    const float* Wvip = (const float*)d_in[6];
    const float* Wo   = (const float*)d_in[7];
    const float* bo   = (const float*)d_in[8];

    char* w = (char*)d_ws;
    size_t off = 0;
    auto alloc = [&](size_t bytes) {
        char* pp = w + off;
        off += (bytes + 255) & ~(size_t)255;
        return pp;
    };
    unsigned short* hs_bf   = (unsigned short*)alloc(16384ull * 1280 * 2);
    unsigned short* q_bf    = (unsigned short*)alloc(16384ull * 1280 * 2);
    unsigned short* at_bf   = (unsigned short*)alloc(16384ull * 1280 * 2);
    unsigned short* text_pad= (unsigned short*)alloc(384ull * 2048 * 2);
    unsigned short* ip_pad  = (unsigned short*)alloc(128ull * 2048 * 2);
    unsigned short* Wq_bf   = (unsigned short*)alloc(1280ull * 1280 * 2);
    unsigned short* Wk_bf   = (unsigned short*)alloc(1280ull * 2048 * 2);
    unsigned short* Wv_bf   = (unsigned short*)alloc(1280ull * 2048 * 2);
    unsigned short* Wkip_bf = (unsigned short*)alloc(1280ull * 2048 * 2);
    unsigned short* Wvip_bf = (unsigned short*)alloc(1280ull * 2048 * 2);
    unsigned short* Wo_bf   = (unsigned short*)alloc(1280ull * 1280 * 2);
    unsigned short* kt  = (unsigned short*)alloc(384ull * 1280 * 2);
    unsigned short* vtT = (unsigned short*)alloc(1280ull * 512 * 2);
    unsigned short* kip = (unsigned short*)alloc(128ull * 1280 * 2);
    unsigned short* ipT = (unsigned short*)alloc(1280ull * 256 * 2);

    // hs convert (big, own launch)
    cvt_f32_bf16<<<dim3(20480, 1, 1), 256, 0, stream>>>(hs, hs_bf, 16384 * 1280 / 4);

    // encoder states -> zero-padded dense text/ip buffers
    cvt_ehs<<<dim3(1024, 1, 1), 256, 0, stream>>>(ehs, text_pad, ip_pad);

    // weight converts in one launch (6 jobs)
    CvtJobs cj{};
    cj.j[0] = CvtJob{Wq,   Wq_bf,   1280 * 1280 / 4};
    cj.j[1] = CvtJob{Wk,   Wk_bf,   1280 * 2048 / 4};
    cj.j[2] = CvtJob{Wv,   Wv_bf,   1280 * 2048 / 4};
    cj.j[3] = CvtJob{Wkip, Wkip_bf, 1280 * 2048 / 4};
    cj.j[4] = CvtJob{Wvip, Wvip_bf, 1280 * 2048 / 4};
    cj.j[5] = CvtJob{Wo,   Wo_bf,   1280 * 1280 / 4};
    cvt_multi<<<dim3(2560, 6, 1), 256, 0, stream>>>(cj);

    // q-proj + k/v projections in ONE flat dispatch.
    // V projections computed TRANSPOSED (A=Wv, B=tokens) so attention reads
    // V^T directly from global. Block counts: kt 10, kip 5, vT 10, vipT 5,
    // q 320 -> 350 total.
    GArgs g1{};
    g1.j[0] = GJob{text_pad, Wk_bf,   (void*)kt,    384, 2048, 1280, 5, 1280,  0};
    g1.j[1] = GJob{ip_pad,   Wkip_bf, (void*)kip,   128, 2048, 1280, 5, 1280, 10};
    g1.j[2] = GJob{Wv_bf,    text_pad,(void*)vtT,  1280, 2048,  384, 2,  512, 15};
    g1.j[3] = GJob{Wvip_bf,  ip_pad,  (void*)ipT,  1280, 2048,  128, 1,  256, 25};
    g1.j[4] = GJob{hs_bf,    Wq_bf,   (void*)q_bf,16384, 1280, 1280, 5, 1280, 30};
    gemm256<false><<<dim3(350, 1, 1), 512, 0, stream>>>(g1, nullptr);

    // fused MFMA attention (text + ip, blend, odd-batch ip add)
    attn_mfma<<<dim3(128, 20, 2), 256, 0, stream>>>(q_bf, kt, vtT, kip, ipT, at_bf);

    // out = attn @ Wo^T + bo  (f32 output), 64x5 = 320 blocks
    GArgs g2{};
    g2.j[0] = GJob{at_bf, Wo_bf, d_out, 16384, 1280, 1280, 5, 1280, 0};
    for (int t = 1; t < 5; ++t) g2.j[t].bstart = 0x7fffffff;
    gemm256<true><<<dim3(320, 1, 1), 512, 0, stream>>>(g2, bo);
}

// Round 3
// 439.550 us; speedup vs baseline: 1.0315x; 1.0012x over previous
//
#include <hip/hip_runtime.h>
#include <cstdint>

// ---------------------------------------------------------------------------
// Types / helpers
// ---------------------------------------------------------------------------
typedef float floatx4 __attribute__((ext_vector_type(4)));
typedef __bf16 bf16x8 __attribute__((ext_vector_type(8)));

typedef const __attribute__((address_space(1))) void* gas_cvp;
typedef __attribute__((address_space(3))) void* las_vp;

__device__ __forceinline__ float bflo(unsigned int u) {
    return __builtin_bit_cast(float, u << 16);
}
__device__ __forceinline__ float bfhi(unsigned int u) {
    return __builtin_bit_cast(float, u & 0xffff0000u);
}
__device__ __forceinline__ unsigned short f2bf(float f) {
    unsigned int u = __builtin_bit_cast(unsigned int, f);
    u += 0x7fffu + ((u >> 16) & 1u);   // RNE (finite inputs)
    return (unsigned short)(u >> 16);
}
__device__ __forceinline__ bf16x8 ld8(const unsigned short* p) {
    return __builtin_bit_cast(bf16x8, *(const uint4*)p);
}
__device__ __forceinline__ floatx4 mfma32(bf16x8 a, bf16x8 b, floatx4 c) {
    return __builtin_amdgcn_mfma_f32_16x16x32_bf16(a, b, c, 0, 0, 0);
}
// async global->LDS, 16B per lane. LDS dest = wave-uniform base + lane*16.
__device__ __forceinline__ void load_lds16(const void* g, void* l) {
    __builtin_amdgcn_global_load_lds(
        (gas_cvp)(unsigned long long)g,
        (las_vp)(unsigned int)(unsigned long long)l,
        16, 0, 0);
}

// ---------------------------------------------------------------------------
// f32 -> bf16 converts
// ---------------------------------------------------------------------------
__global__ void cvt_f32_bf16(const float* __restrict__ in,
                             unsigned short* __restrict__ out, int n4) {
    int i = blockIdx.x * 256 + threadIdx.x;
    if (i < n4) {
        float4 v = ((const float4*)in)[i];
        ushort4 o;
        o.x = f2bf(v.x); o.y = f2bf(v.y); o.z = f2bf(v.z); o.w = f2bf(v.w);
        ((ushort4*)out)[i] = o;
    }
}

struct CvtJob { const float* src; unsigned short* dst; int n4; };
struct CvtJobs { CvtJob j[6]; };

__global__ void cvt_multi(CvtJobs jobs) {
    CvtJob jb = jobs.j[blockIdx.y];
    int i = blockIdx.x * 256 + threadIdx.x;
    if (i < jb.n4) {
        float4 v = ((const float4*)jb.src)[i];
        ushort4 o;
        o.x = f2bf(v.x); o.y = f2bf(v.y); o.z = f2bf(v.z); o.w = f2bf(v.w);
        ((ushort4*)jb.dst)[i] = o;
    }
}

// ehs [4][97][2048] f32 -> text_pad [4*96][2048] bf16 (rows 77..95/batch = 0)
//                       -> ip_pad   [4*32][2048] bf16 (rows 20..31/batch = 0)
__global__ void cvt_ehs(const float* __restrict__ ehs,
                        unsigned short* __restrict__ text,
                        unsigned short* __restrict__ ip) {
    int i = blockIdx.x * 256 + threadIdx.x;   // ushort4 units
    if (i < 384 * 512) {
        int r = i >> 9, c = i & 511;
        int b = r / 96, t = r - b * 96;
        ushort4 o = {0, 0, 0, 0};
        if (t < 77) {
            float4 v = *(const float4*)&ehs[((size_t)(b * 97 + t)) * 2048 + c * 4];
            o.x = f2bf(v.x); o.y = f2bf(v.y); o.z = f2bf(v.z); o.w = f2bf(v.w);
        }
        ((ushort4*)text)[i] = o;
    } else {
        int i2 = i - 384 * 512;
        if (i2 < 128 * 512) {
            int r = i2 >> 9, c = i2 & 511;
            int b = r >> 5, t = r & 31;
            ushort4 o = {0, 0, 0, 0};
            if (t < 20) {
                float4 v = *(const float4*)&ehs[((size_t)(b * 97 + 77 + t)) * 2048 + c * 4];
                o.x = f2bf(v.x); o.y = f2bf(v.y); o.z = f2bf(v.z); o.w = f2bf(v.w);
            }
            ((ushort4*)ip)[i2] = o;
        }
    }
}

// ---------------------------------------------------------------------------
// 256x256 BT GEMM, 1-barrier-per-K-tile loop:  C[m,n] = sum_k A[m,k]*B[n,k]
// 512 threads = 8 waves (2M x 4N), BK=64, LDS 128 KiB double-buffered.
// Per K-tile: stage FULL tile u+1 -> idle buffer (8 gloads, hazard-free:
// its readers finished at iter u-1's barrier), sched_barrier pin, then
// 24 ds_read_b128 + 64 MFMA (kk-split, register-lean), then ONE
// vmcnt(0)+s_barrier (loads are a full iteration old -> drain ~free).
// LDS 16x32-subtiled with chunk^row XOR swizzle (bank-conflict-free b128),
// applied on the pre-swizzled GLOBAL source (gload_lds writes linearly).
// ---------------------------------------------------------------------------
struct GJob {
    const unsigned short* A;
    const unsigned short* B;
    void* C;
    int M, K;
    int Bn;      // B row count (clamp)
    int nt;      // N tiles of 256
    int ldc;     // C leading dimension
    int bstart;  // first flat block id
};
struct GArgs { GJob j[5]; };

template <bool F32OUT>
__global__ __launch_bounds__(512, 2) void gemm256(GArgs args,
                                                  const float* __restrict__ bias) {
    const int tid = threadIdx.x;
    int jid = 0;
#pragma unroll
    for (int t = 1; t < 5; ++t)
        if ((int)blockIdx.x >= args.j[t].bstart) jid = t;
    const GJob jb = args.j[jid];
    const int K = jb.K;
    int b = (int)blockIdx.x - jb.bstart;
    {
        const int mt = (jb.M + 255) >> 8;
        const int nblk = mt * jb.nt;
        if ((nblk & 7) == 0) b = (b & 7) * (nblk >> 3) + (b >> 3);  // XCD swizzle
    }
    const int by = b / jb.nt, bx = b - by * jb.nt;

    __shared__ unsigned short ldsA[32768];   // 64 KiB
    __shared__ unsigned short ldsB[32768];   // 64 KiB

    // staging decode: thread t stages 16B; stored chunk = (t&3), logical chunk
    // = stored ^ ((r&6)>>1)  (involution applied on global source address)
    const int srow   = ((tid >> 7) << 4) + ((tid >> 2) & 15);          // 0..63
    const int schunk = ((tid & 3) << 4) ^ (((tid >> 2) & 6) << 3);     // bytes
    const int scol   = (((tid >> 6) & 1) << 5) + (schunk >> 1);        // elems

    const int Mloc = jb.M, BnL = jb.Bn;

    const unsigned short* pA[2][2];
    const unsigned short* pB[2][2];
    unsigned short* dA[2][2];
    unsigned short* dB[2][2];
#pragma unroll
    for (int h = 0; h < 2; ++h)
#pragma unroll
        for (int j = 0; j < 2; ++j) {
            const int r = h * 128 + j * 64 + srow;
            int ra = by * 256 + r;  ra = (ra < Mloc) ? ra : (Mloc - 1);
            int rb2 = bx * 256 + r; rb2 = (rb2 < BnL) ? rb2 : (BnL - 1);
            pA[h][j] = jb.A + (size_t)ra * K + scol;
            pB[h][j] = jb.B + (size_t)rb2 * K + scol;
            dA[h][j] = &ldsA[h * 8192 + j * 4096 + tid * 8];
            dB[h][j] = &ldsB[h * 8192 + j * 4096 + tid * 8];
        }

    // fragment-read decode
    const int lane = tid & 63, fr = lane & 15, g = lane >> 4;
    const int w = tid >> 6, wr = w & 1, wc = w >> 1;
    const int rb   = fr * 32 + ((g * 8) ^ ((fr & 6) << 2));            // shorts
    const int aoff = wr * 8192 + rb;
    const int boff = (wc >> 1) * 8192 + (wc & 1) * 4096 + rb;

    floatx4 acc[8][4] = {};

    const int KT = K >> 6;

    // prologue: stage tile0 -> buffer0
#pragma unroll
    for (int h = 0; h < 2; ++h)
#pragma unroll
        for (int j = 0; j < 2; ++j) {
            load_lds16(pA[h][j], dA[h][j]);
            load_lds16(pB[h][j], dB[h][j]);
        }
    asm volatile("s_waitcnt vmcnt(0)" ::: "memory");
    __builtin_amdgcn_s_barrier();

    for (int u = 0; u < KT; ++u) {
        const int pb = (u & 1) << 14;     // read buffer base (shorts)
        const int qb = pb ^ 16384;        // stage target (idle buffer)
        const int k1 = (u + 1 < KT) ? (u + 1) : (KT - 1);

        // stage FULL tile u+1 -> qb (hazard-free; qb unused this iter)
#pragma unroll
        for (int h = 0; h < 2; ++h)
#pragma unroll
            for (int j = 0; j < 2; ++j) {
                load_lds16(pA[h][j] + (size_t)k1 * 64, dA[h][j] + qb);
                load_lds16(pB[h][j] + (size_t)k1 * 64, dB[h][j] + qb);
            }
        __builtin_amdgcn_sched_barrier(0);   // pin gloads before compute

        // compute tile u from pb: kk-split keeps operand regs at 48 VGPR
#pragma unroll
        for (int kk = 0; kk < 2; ++kk) {
            bf16x8 af[8], bfr[4];
#pragma unroll
            for (int mi = 0; mi < 8; ++mi)
                af[mi] = *(const bf16x8*)&ldsA[pb + aoff + (mi * 2 + kk) * 512];
#pragma unroll
            for (int nf = 0; nf < 4; ++nf)
                bfr[nf] = *(const bf16x8*)&ldsB[pb + boff + (nf * 2 + kk) * 512];
            __builtin_amdgcn_s_setprio(1);
#pragma unroll
            for (int mi = 0; mi < 8; ++mi)
#pragma unroll
                for (int nf = 0; nf < 4; ++nf)
                    acc[mi][nf] = mfma32(af[mi], bfr[nf], acc[mi][nf]);
            __builtin_amdgcn_s_setprio(0);
        }

        // publish tile u+1: loads are a full iteration old -> drain ~free
        asm volatile("s_waitcnt vmcnt(0)" ::: "memory");
        __builtin_amdgcn_s_barrier();
    }

    // epilogue
    const int colBase = bx * 256 + wc * 64;
    const int rowBase = by * 256 + wr * 128;
    const int ldc = jb.ldc;
    float bv[4] = {};
    if (F32OUT) {
#pragma unroll
        for (int nf = 0; nf < 4; ++nf) bv[nf] = bias[colBase + nf * 16 + fr];
    }
#pragma unroll
    for (int mi = 0; mi < 8; ++mi) {
#pragma unroll
        for (int nf = 0; nf < 4; ++nf) {
            const int col  = colBase + nf * 16 + fr;
            const int row0 = rowBase + mi * 16 + g * 4;
#pragma unroll
            for (int r = 0; r < 4; ++r) {
                const int row = row0 + r;
                if (row < Mloc) {
                    float v = acc[mi][nf][r];
                    if (F32OUT)
                        ((float*)jb.C)[(size_t)row * ldc + col] = v + bv[nf];
                    else
                        ((unsigned short*)jb.C)[(size_t)row * ldc + col] = f2bf(v);
                }
            }
        }
    }
}

// ---------------------------------------------------------------------------
// MFMA attention. Block = (q-tile of 32 rows) x (head) x (batch pair).
// K is read from kt [4*96][1280] (zero-padded keys), V^T directly from global
// vtT [1280][512] (col = b*96+key, zero-padded) -- no LDS V staging.
// ---------------------------------------------------------------------------
#define NT 77
#define NI 20

__global__ __launch_bounds__(256, 4) void attn_mfma(
    const unsigned short* __restrict__ q,    // [4*4096][1280]
    const unsigned short* __restrict__ kt,   // [4*96][1280]
    const unsigned short* __restrict__ vtT,  // [1280][512]
    const unsigned short* __restrict__ kip,  // [4*32][1280]
    const unsigned short* __restrict__ ipT,  // [1280][256]
    unsigned short* __restrict__ outp)       // [4*4096][1280]
{
    const int tid = threadIdx.x;
    const int qt = blockIdx.x;
    const int h  = blockIdx.y;
    const int pz = blockIdx.z;
    const int b0 = 2 * pz;
    const int lane  = tid & 63;
    const int w     = tid >> 6;
    const int bi    = w >> 1;
    const int strip = (w & 1) * 16;
    const int fr = lane & 15;
    const int g  = lane >> 4;

    __shared__ unsigned short sP[2][32][104];

    // zero P pad cols 80..103 (PV third chunk covers keys 64..95)
    for (int i = tid; i < 2 * 32 * 24; i += 256) {
        int b = i / (32 * 24); int rem = i % (32 * 24);
        sP[b][rem / 24][80 + rem % 24] = 0;
    }

    const size_t qbase = ((size_t)((b0 + bi) * 4096 + qt * 32 + strip + fr)) * 1280 + h * 64;
    bf16x8 aq0 = ld8(&q[qbase + g * 8]);
    bf16x8 aq1 = ld8(&q[qbase + 32 + g * 8]);

    floatx4 sc[5] = {};
#pragma unroll
    for (int t = 0; t < 5; t++) {
        int key = t * 16 + fr;                      // <= 79 < 96 (padded)
        const size_t kb = ((size_t)((b0 + bi) * 96 + key)) * 1280 + h * 64;
        sc[t] = mfma32(aq0, ld8(&kt[kb + g * 8]), sc[t]);
        sc[t] = mfma32(aq1, ld8(&kt[kb + 32 + g * 8]), sc[t]);
    }

#pragma unroll
    for (int r = 0; r < 4; r++) {
        float m = -1e30f;
#pragma unroll
        for (int t = 0; t < 5; t++) {
            float v = sc[t][r] * 0.125f;
            if (t == 4 && fr >= 13) v = -1e30f;     // keys 77..79 masked
            sc[t][r] = v;
            m = fmaxf(m, v);
        }
        m = fmaxf(m, __shfl_xor(m, 1));
        m = fmaxf(m, __shfl_xor(m, 2));
        m = fmaxf(m, __shfl_xor(m, 4));
        m = fmaxf(m, __shfl_xor(m, 8));
        float sum = 0.f;
#pragma unroll
        for (int t = 0; t < 5; t++) {
            float e = __expf(sc[t][r] - m);
            sc[t][r] = e;
            sum += e;
        }
        sum += __shfl_xor(sum, 1);
        sum += __shfl_xor(sum, 2);
        sum += __shfl_xor(sum, 4);
        sum += __shfl_xor(sum, 8);
        float inv = 1.f / sum;
#pragma unroll
        for (int t = 0; t < 5; t++)
            sP[bi][strip + g * 4 + r][t * 16 + fr] = f2bf(sc[t][r] * inv);
    }
    __syncthreads();

    // blend: p[b0+1] = 0.5*(p[b0] + p[b0+1])
    {
        unsigned int* p0 = (unsigned int*)&sP[0][0][0];
        unsigned int* p1 = (unsigned int*)&sP[1][0][0];
        for (int i = tid; i < 32 * 104 / 2; i += 256) {
            unsigned int a = p0[i], b = p1[i];
            unsigned short r0 = f2bf(0.5f * (bflo(a) + bflo(b)));
            unsigned short r1 = f2bf(0.5f * (bfhi(a) + bfhi(b)));
            p1[i] = (unsigned int)r0 | ((unsigned int)r1 << 16);
        }
    }
    __syncthreads();

    floatx4 accO[4] = {};
    {
        const unsigned short* prow = &sP[bi][strip + fr][0];
        bf16x8 pa0 = ld8(prow + g * 8);
        bf16x8 pa1 = ld8(prow + 32 + g * 8);
        bf16x8 pa2 = ld8(prow + 64 + g * 8);
        const int vcol = (b0 + bi) * 96;
#pragma unroll
        for (int dt = 0; dt < 4; dt++) {
            const unsigned short* vrow = &vtT[(size_t)(h * 64 + dt * 16 + fr) * 512 + vcol];
            accO[dt] = mfma32(pa0, ld8(vrow + g * 8), accO[dt]);
            accO[dt] = mfma32(pa1, ld8(vrow + 32 + g * 8), accO[dt]);
            accO[dt] = mfma32(pa2, ld8(vrow + 64 + g * 8), accO[dt]);
        }
    }

    floatx4 si[2] = {};
#pragma unroll
    for (int t = 0; t < 2; t++) {
        int key = t * 16 + fr;                      // < 32 (padded)
        const size_t kb = ((size_t)((b0 + bi) * 32 + key)) * 1280 + h * 64;
        si[t] = mfma32(aq0, ld8(&kip[kb + g * 8]), si[t]);
        si[t] = mfma32(aq1, ld8(&kip[kb + 32 + g * 8]), si[t]);
    }
#pragma unroll
    for (int r = 0; r < 4; r++) {
        float v0 = si[0][r] * 0.125f;
        float v1 = (fr >= 4) ? -1e30f : si[1][r] * 0.125f;
        float m = fmaxf(v0, v1);
        m = fmaxf(m, __shfl_xor(m, 1));
        m = fmaxf(m, __shfl_xor(m, 2));
        m = fmaxf(m, __shfl_xor(m, 4));
        m = fmaxf(m, __shfl_xor(m, 8));
        float e0 = __expf(v0 - m), e1 = __expf(v1 - m);
        float s = e0 + e1;
        s += __shfl_xor(s, 1);
        s += __shfl_xor(s, 2);
        s += __shfl_xor(s, 4);
        s += __shfl_xor(s, 8);
        float inv = 1.f / s;
        si[0][r] = e0 * inv;
        si[1][r] = e1 * inv;
    }
    __syncthreads();

#pragma unroll
    for (int r = 0; r < 4; r++) {
        sP[bi][strip + g * 4 + r][fr]      = f2bf(si[0][r]);
        sP[bi][strip + g * 4 + r][16 + fr] = f2bf(si[1][r]);
    }
    __syncthreads();

    for (int i = tid; i < 32 * 16; i += 256) {
        int r = i >> 4, kk = i & 15;
        unsigned int* p0 = (unsigned int*)&sP[0][r][0];
        unsigned int* p1 = (unsigned int*)&sP[1][r][0];
        unsigned int a = p0[kk], b = p1[kk];
        unsigned short r0 = f2bf(0.5f * (bflo(a) + bflo(b)));
        unsigned short r1 = f2bf(0.5f * (bfhi(a) + bfhi(b)));
        p1[kk] = (unsigned int)r0 | ((unsigned int)r1 << 16);
    }
    __syncthreads();

    if (bi == 1) {
        const unsigned short* prow = &sP[1][strip + fr][0];
        bf16x8 pip = ld8(prow + g * 8);
        const int icol = (b0 + 1) * 32;
#pragma unroll
        for (int dt = 0; dt < 4; dt++)
            accO[dt] = mfma32(pip,
                              ld8(&ipT[(size_t)(h * 64 + dt * 16 + fr) * 256 + icol + g * 8]),
                              accO[dt]);
    }

    const size_t orow0 = (size_t)((b0 + bi) * 4096 + qt * 32 + strip);
#pragma unroll
    for (int dt = 0; dt < 4; dt++) {
        int col = h * 64 + dt * 16 + fr;
#pragma unroll
        for (int r = 0; r < 4; r++)
            outp[(orow0 + g * 4 + r) * 1280 + col] = f2bf(accO[dt][r]);
    }
}

// ---------------------------------------------------------------------------
// Host launch
// ---------------------------------------------------------------------------
extern "C" void kernel_launch(void* const* d_in, const int* in_sizes, int n_in,
                              void* d_out, int out_size, void* d_ws, size_t ws_size,
                              hipStream_t stream) {
    const float* hs   = (const float*)d_in[0];
    const float* ehs  = (const float*)d_in[1];
    const float* Wq   = (const float*)d_in[2];
    const float* Wk   = (const float*)d_in[3];
    const float* Wv   = (const float*)d_in[4];
    const float* Wkip = (const float*)d_in[5];
    const float* Wvip = (const float*)d_in[6];
    const float* Wo   = (const float*)d_in[7];
    const float* bo   = (const float*)d_in[8];

    char* w = (char*)d_ws;
    size_t off = 0;
    auto alloc = [&](size_t bytes) {
        char* pp = w + off;
        off += (bytes + 255) & ~(size_t)255;
        return pp;
    };
    unsigned short* hs_bf   = (unsigned short*)alloc(16384ull * 1280 * 2);
    unsigned short* q_bf    = (unsigned short*)alloc(16384ull * 1280 * 2);
    unsigned short* at_bf   = (unsigned short*)alloc(16384ull * 1280 * 2);
    unsigned short* text_pad= (unsigned short*)alloc(384ull * 2048 * 2);
    unsigned short* ip_pad  = (unsigned short*)alloc(128ull * 2048 * 2);
    unsigned short* Wq_bf   = (unsigned short*)alloc(1280ull * 1280 * 2);
    unsigned short* Wk_bf   = (unsigned short*)alloc(1280ull * 2048 * 2);
    unsigned short* Wv_bf   = (unsigned short*)alloc(1280ull * 2048 * 2);
    unsigned short* Wkip_bf = (unsigned short*)alloc(1280ull * 2048 * 2);
    unsigned short* Wvip_bf = (unsigned short*)alloc(1280ull * 2048 * 2);
    unsigned short* Wo_bf   = (unsigned short*)alloc(1280ull * 1280 * 2);
    unsigned short* kt  = (unsigned short*)alloc(384ull * 1280 * 2);
    unsigned short* vtT = (unsigned short*)alloc(1280ull * 512 * 2);
    unsigned short* kip = (unsigned short*)alloc(128ull * 1280 * 2);
    unsigned short* ipT = (unsigned short*)alloc(1280ull * 256 * 2);

    // hs convert (big, own launch)
    cvt_f32_bf16<<<dim3(20480, 1, 1), 256, 0, stream>>>(hs, hs_bf, 16384 * 1280 / 4);

    // encoder states -> zero-padded dense text/ip buffers
    cvt_ehs<<<dim3(1024, 1, 1), 256, 0, stream>>>(ehs, text_pad, ip_pad);

    // weight converts in one launch (6 jobs)
    CvtJobs cj{};
    cj.j[0] = CvtJob{Wq,   Wq_bf,   1280 * 1280 / 4};
    cj.j[1] = CvtJob{Wk,   Wk_bf,   1280 * 2048 / 4};
    cj.j[2] = CvtJob{Wv,   Wv_bf,   1280 * 2048 / 4};
    cj.j[3] = CvtJob{Wkip, Wkip_bf, 1280 * 2048 / 4};
    cj.j[4] = CvtJob{Wvip, Wvip_bf, 1280 * 2048 / 4};
    cj.j[5] = CvtJob{Wo,   Wo_bf,   1280 * 1280 / 4};
    cvt_multi<<<dim3(2560, 6, 1), 256, 0, stream>>>(cj);

    // q-proj + k/v projections in ONE flat dispatch.
    // V projections computed TRANSPOSED (A=Wv, B=tokens) so attention reads
    // V^T directly from global. Block counts: kt 10, kip 5, vT 10, vipT 5,
    // q 320 -> 350 total.
    GArgs g1{};
    g1.j[0] = GJob{text_pad, Wk_bf,   (void*)kt,    384, 2048, 1280, 5, 1280,  0};
    g1.j[1] = GJob{ip_pad,   Wkip_bf, (void*)kip,   128, 2048, 1280, 5, 1280, 10};
    g1.j[2] = GJob{Wv_bf,    text_pad,(void*)vtT,  1280, 2048,  384, 2,  512, 15};
    g1.j[3] = GJob{Wvip_bf,  ip_pad,  (void*)ipT,  1280, 2048,  128, 1,  256, 25};
    g1.j[4] = GJob{hs_bf,    Wq_bf,   (void*)q_bf,16384, 1280, 1280, 5, 1280, 30};
    gemm256<false><<<dim3(350, 1, 1), 512, 0, stream>>>(g1, nullptr);

    // fused MFMA attention (text + ip, blend, odd-batch ip add)
    attn_mfma<<<dim3(128, 20, 2), 256, 0, stream>>>(q_bf, kt, vtT, kip, ipT, at_bf);

    // out = attn @ Wo^T + bo  (f32 output), 64x5 = 320 blocks
    GArgs g2{};
    g2.j[0] = GJob{at_bf, Wo_bf, d_out, 16384, 1280, 1280, 5, 1280, 0};
    for (int t = 1; t < 5; ++t) g2.j[t].bstart = 0x7fffffff;
    gemm256<true><<<dim3(320, 1, 1), 512, 0, stream>>>(g2, bo);
}